// Round 9
// baseline (91.248 us; speedup 1.0000x reference)
//
#include <hip/hip_runtime.h>
#include <math.h>

#define NS 2000
#define NPAD 2048
#define EPS_F 1.1920928955078125e-07f
#define BLOCK 1024
#define WAVES (BLOCK / 64)        // 16 waves per block
#define EPW 4                     // elements per wave (shared LDS stream)
#define LOG2E 1.4426950408889634f

// 2^x via v_exp_f32 (named wrapper: __exp2f collides with glibc math.h).
__device__ __forceinline__ float exp2_hw(float x) {
    return __builtin_amdgcn_exp2f(x);
}

// x += dpp_moved(x): old=0, bound_ctrl=1 -> OOB/unselected lanes add 0.
// Verified on HW in rounds 7-8.
template <int CTRL, int RMASK>
__device__ __forceinline__ float dpp_add(float x) {
    int t = __builtin_amdgcn_update_dpp(0, __float_as_int(x), CTRL, RMASK, 0xf, true);
    return x + __int_as_float(t);
}

// Wave64 inclusive add-scan: 6 VALU ops, zero DS-pipe traffic.
__device__ __forceinline__ float scan64(float x) {
    x = dpp_add<0x111, 0xf>(x);   // row_shr:1
    x = dpp_add<0x112, 0xf>(x);   // row_shr:2
    x = dpp_add<0x114, 0xf>(x);   // row_shr:4
    x = dpp_add<0x118, 0xf>(x);   // row_shr:8
    x = dpp_add<0x142, 0xa>(x);   // row_bcast:15 -> rows 1,3
    x = dpp_add<0x143, 0xc>(x);   // row_bcast:31 -> rows 2,3
    return x;
}

// Independent inclusive scan within each 32-lane half.
__device__ __forceinline__ float scan32(float x) {
    x = dpp_add<0x111, 0xf>(x);
    x = dpp_add<0x112, 0xf>(x);
    x = dpp_add<0x114, 0xf>(x);
    x = dpp_add<0x118, 0xf>(x);
    x = dpp_add<0x142, 0xa>(x);   // row_bcast:15 within each half
    return x;
}

__device__ __forceinline__ float bcast_lane(float x, int lane_sgpr) {
    return __int_as_float(__builtin_amdgcn_readlane(__float_as_int(x), lane_sgpr));
}

// Kernel 1: build two table views in workspace.
//   tabT: transposed pairs. float4 slot (kk*64 + l) holds points 32l+2kk and
//         32l+2kk+1 as (a0, lw0, a1, lw1) -> pass-1 lane-consecutive b128.
//   tab2: linear float2 (a, lw) -> cooperative chunk re-eval + epilogue.
// a = atanh-table value, lw = log2(1/(1-x^2)); pads get lw=-1000 => q=0.
__global__ void build_table(float2* __restrict__ tabT, float2* __restrict__ tab2) {
    int i = blockIdx.x * blockDim.x + threadIdx.x;
    if (i >= NPAD) return;
    float a = 0.0f, lw = -1000.0f;
    if (i < NS) {
        const double y0 = -0.9999, y1 = 0.9999;
        const double step = (y1 - y0) / 1999.0;
        float x = (i == NS - 1) ? (float)y1 : (float)(y0 + (double)i * step);
        float ratio = (1.0f + x) / (1.0f - x) + EPS_F;   // ref: (1+x)/(1-x)+EPS
        a = 0.5f * logf(ratio);                          // atanh_x
        float w = 1.0f / (1.0f - x * x);                 // 1/(1-x^2), >= 1
        lw = log2f(w);
    }
    tab2[i] = make_float2(a, lw);
    int l = i >> 5, k = i & 31, kk = k >> 1, h = k & 1;
    tabT[(kk * 64 + l) * 2 + h] = make_float2(a, lw);
}

// Kernel 2: each wave processes EPW=4 elements SIMULTANEOUSLY against one
// shared LDS table stream: each ds_read_b128 feeds 8 fma->exp2 chains
// instead of 2, cutting DS-pipe cycles/element 4x (the round-8 bottleneck).
// Per-element state (~8 regs) stays in VGPRs; nothing invariant to remat.
// All scans/broadcasts are DPP/readlane (VALU/SALU).
__global__ __launch_bounds__(BLOCK) void sample_kernel(
    const float* __restrict__ mean, const float* __restrict__ stdv,
    const float* __restrict__ uni, const float4* __restrict__ gT,
    const float4* __restrict__ gP,
    float* __restrict__ out_vals, float* __restrict__ out_probs, int nElem) {
    __shared__ float4 sT[NPAD / 2];     // transposed pair view (16 KB)
    __shared__ float4 sPbuf[NPAD / 2];  // linear view (16 KB)
    const float2* sP = (const float2*)sPbuf;
    {
        int t = threadIdx.x;            // 0..1023 == NPAD/2-1
        sT[t] = gT[t];
        sPbuf[t] = gP[t];
    }
    __syncthreads();

    const int lane = threadIdx.x & 63;
    const int wid = __builtin_amdgcn_readfirstlane(threadIdx.x >> 6);
    const int elemBase = (blockIdx.x * WAVES + wid) * EPW;
    if (elemBase >= nElem) return;

    // Per-element parameters (wave-uniform scalar loads).
    float mu[EPW], rd2[EPW], nc[EPW], uu[EPW];
    #pragma unroll
    for (int j = 0; j < EPW; j++) {
        const int elem = elemBase + j;
        mu[j] = mean[elem];
        float sg = stdv[elem] + EPS_F;             // ref: std + EPS
        uu[j] = uni[elem];
        float sg2 = sg * sg;
        rd2[j] = LOG2E / (-2.0f * sg2);            // exp(x)=exp2(x*log2e)
        nc[j] = 1.0f / sqrtf(6.2831853071795864f * sg2);
    }

    // Pass 1: per-lane sums of q_i = exp2((a-mu)^2*rd2 + lw) for all EPW
    // elements against ONE table stream. Lane l owns points [32l, 32l+32).
    float s0[EPW], s1[EPW];
    #pragma unroll
    for (int j = 0; j < EPW; j++) { s0[j] = 0.0f; s1[j] = 0.0f; }
    #pragma unroll
    for (int kk = 0; kk < 16; kk++) {
        float4 v = sT[kk * 64 + lane];             // 2 points, one b128
        #pragma unroll
        for (int j = 0; j < EPW; j++) {
            float d0 = v.x - mu[j];
            s0[j] += exp2_hw(fmaf(d0 * d0, rd2[j], v.y));
            float d1 = v.z - mu[j];
            s1[j] += exp2_hw(fmaf(d1 * d1, rd2[j], v.w));
        }
    }

    // Selection + epilogue per element (DPP scans, 2 small LDS reads each).
    #pragma unroll
    for (int j = 0; j < EPW; j++) {
        const int elem = elemBase + j;
        float s = s0[j] + s1[j];
        float incl = scan64(s);
        const float S = bcast_lane(incl, 63);      // wave-uniform q-sum
        const float denom = S * nc[j] + EPS_F;     // ref: sum(probs)+EPS
        const float tt = (uu[j] * denom) / nc[j];  // threshold in q-space

        unsigned long long mgt = __ballot(incl > tt);
        int jstar = mgt ? __builtin_ctzll(mgt) : 64;
        int jj = (jstar < 64) ? jstar : 0;
        float exclb = bcast_lane(incl - s, jj);    // exclusive chunk offset

        // Cooperative re-eval of chunk jj (both 32-lane halves duplicate;
        // same-address LDS pairs broadcast, conflict-free).
        int c = lane & 31;
        float2 al = sP[jj * 32 + c];
        float d = al.x - mu[j];
        float cum = scan32(exp2_hw(fmaf(d * d, rd2[j], al.y)));
        cum += exclb;
        unsigned int m2 = (unsigned int)(__ballot(cum > tt) & 0xffffffffULL);
        int sub = m2 ? (int)__builtin_ctz(m2) : 32;
        int idx = (jstar >= 64) ? 0 : min(jj * 32 + sub, NS - 1);

        if (lane == 0) {
            float2 al2 = sP[idx];
            float dd = al2.x - mu[j];
            float pk = exp2_hw(fmaf(dd * dd, rd2[j], al2.y)) * nc[j];
            const double y0 = -0.9999, y1 = 0.9999;
            const double step = (y1 - y0) / 1999.0;
            float gv = (idx == NS - 1) ? (float)y1
                                       : (float)(y0 + (double)idx * step);
            out_vals[elem] = gv;
            out_probs[elem] = pk / denom;          // ref: probs/(sum+EPS)
        }
    }
}

extern "C" void kernel_launch(void* const* d_in, const int* in_sizes, int n_in,
                              void* d_out, int out_size, void* d_ws, size_t ws_size,
                              hipStream_t stream) {
    const float* mean = (const float*)d_in[0];
    const float* stdv = (const float*)d_in[1];
    const float* uni = (const float*)d_in[2];
    float* out = (float*)d_out;
    const int nElem = in_sizes[0];                 // 4096*16 = 65536
    float* out_vals = out;
    float* out_probs = out + nElem;

    float2* tabT = (float2*)d_ws;                  // 2048 float2 = 16 KB
    float2* tab2 = tabT + NPAD;                    // 2048 float2 = 16 KB

    build_table<<<NPAD / 256, 256, 0, stream>>>(tabT, tab2);

    const int elemsPerBlock = WAVES * EPW;         // 64
    const int grid = (nElem + elemsPerBlock - 1) / elemsPerBlock;  // 1024
    sample_kernel<<<grid, BLOCK, 0, stream>>>(mean, stdv, uni,
                                              (const float4*)tabT,
                                              (const float4*)tab2,
                                              out_vals, out_probs, nElem);
}